// Round 1
// baseline (994.554 us; speedup 1.0000x reference)
//
#include <hip/hip_runtime.h>
#include <hip/hip_bf16.h>
#include <cstdint>
#include <cstddef>

typedef __bf16 bf16;
typedef bf16 bf16x8 __attribute__((ext_vector_type(8)));
typedef float f32x4 __attribute__((ext_vector_type(4)));

#define B_CHUNK 32
#define N_TOK 196
#define DIM_ 384
#define HQKV 2304
#define NH 12
#define NPAD 224          // padded token count (m dim), 7*32
#define MROWS (B_CHUNK * N_TOK)   // 6272 = 49*128

// ---------------------------------------------------------------- prep
__global__ __launch_bounds__(256) void prep_kernel(
    const float* __restrict__ qg, const float* __restrict__ qb,
    const float* __restrict__ qm, const float* __restrict__ qv,
    const float* __restrict__ pg, const float* __restrict__ pb,
    const float* __restrict__ pm, const float* __restrict__ pv,
    const float* __restrict__ abias, const int* __restrict__ idxs,
    float* __restrict__ sqkv, float* __restrict__ bqkv,
    float* __restrict__ sproj, float* __restrict__ bproj,
    float* __restrict__ ab)
{
    int i = blockIdx.x * 256 + threadIdx.x;
    if (i < HQKV) {
        float s = qg[i] * rsqrtf(qv[i] + 1e-5f);
        sqkv[i] = s;
        bqkv[i] = qb[i] - qm[i] * s;
    }
    if (i < DIM_) {
        float s = pg[i] * rsqrtf(pv[i] + 1e-5f);
        sproj[i] = s;
        bproj[i] = pb[i] - pm[i] * s;
    }
    if (i < NH * N_TOK * NPAD) {
        int h = i / (N_TOK * NPAD);
        int rem = i - h * (N_TOK * NPAD);
        int n = rem / NPAD;
        int m = rem - n * NPAD;
        ab[i] = (m < N_TOK) ? abias[h * N_TOK + idxs[n * N_TOK + m]] : -1e30f;
    }
}

// ---------------------------------------------------------------- QKV GEMM
// x: [MROWS][384] f32 (chunk), w: [2304][384] f32
// out: qkv_c [B_CHUNK*12][224][192] bf16 (rows >=196 untouched)
__global__ __launch_bounds__(256) void qkv_gemm(
    const float* __restrict__ x, const float* __restrict__ w,
    const float* __restrict__ sq, const float* __restrict__ bq,
    bf16* __restrict__ qkv_c)
{
    __shared__ bf16 As[128 * 40];
    __shared__ bf16 Bs[128 * 40];
    int t = threadIdx.x;
    int m0 = blockIdx.x * 128;
    int n0 = blockIdx.y * 128;
    int lane = t & 63, wid = t >> 6;
    int qr = (wid >> 1) * 64, qc = (wid & 1) * 64;
    int lr = lane & 15, lg = lane >> 4, lk = lg * 8;

    f32x4 acc[4][4];
#pragma unroll
    for (int fi = 0; fi < 4; ++fi)
#pragma unroll
        for (int fj = 0; fj < 4; ++fj)
            acc[fi][fj] = (f32x4){0.f, 0.f, 0.f, 0.f};

    for (int kt = 0; kt < DIM_ / 32; ++kt) {
        int k0 = kt * 32;
#pragma unroll
        for (int i = 0; i < 2; ++i) {
            int c = t + i * 256;
            int r = c >> 2, kk = (c & 3) * 8;
            const float4* sa = (const float4*)(x + (size_t)(m0 + r) * DIM_ + k0 + kk);
            float4 a0 = sa[0], a1 = sa[1];
            bf16x8 va;
            va[0] = (bf16)a0.x; va[1] = (bf16)a0.y; va[2] = (bf16)a0.z; va[3] = (bf16)a0.w;
            va[4] = (bf16)a1.x; va[5] = (bf16)a1.y; va[6] = (bf16)a1.z; va[7] = (bf16)a1.w;
            *(bf16x8*)&As[r * 40 + kk] = va;
            const float4* sb = (const float4*)(w + (size_t)(n0 + r) * DIM_ + k0 + kk);
            float4 b0 = sb[0], b1 = sb[1];
            bf16x8 vb;
            vb[0] = (bf16)b0.x; vb[1] = (bf16)b0.y; vb[2] = (bf16)b0.z; vb[3] = (bf16)b0.w;
            vb[4] = (bf16)b1.x; vb[5] = (bf16)b1.y; vb[6] = (bf16)b1.z; vb[7] = (bf16)b1.w;
            *(bf16x8*)&Bs[r * 40 + kk] = vb;
        }
        __syncthreads();
        bf16x8 a[4], b[4];
#pragma unroll
        for (int f = 0; f < 4; ++f) {
            a[f] = *(bf16x8*)&As[(qr + f * 16 + lr) * 40 + lk];
            b[f] = *(bf16x8*)&Bs[(qc + f * 16 + lr) * 40 + lk];
        }
#pragma unroll
        for (int fi = 0; fi < 4; ++fi)
#pragma unroll
            for (int fj = 0; fj < 4; ++fj)
                acc[fi][fj] = __builtin_amdgcn_mfma_f32_16x16x32_bf16(a[fi], b[fj], acc[fi][fj], 0, 0, 0);
        __syncthreads();
    }

#pragma unroll
    for (int fj = 0; fj < 4; ++fj) {
        int col = n0 + qc + fj * 16 + lr;
        float s = sq[col], bb = bq[col];
        int h = col / 192, cc = col - h * 192;
#pragma unroll
        for (int fi = 0; fi < 4; ++fi) {
            int rb = m0 + qr + fi * 16 + lg * 4;
#pragma unroll
            for (int r = 0; r < 4; ++r) {
                int row = rb + r;
                int bl = row / N_TOK, n = row - bl * N_TOK;
                float v = acc[fi][fj][r] * s + bb;
                qkv_c[((size_t)(bl * NH + h) * NPAD + n) * 192 + cc] = (bf16)v;
            }
        }
    }
}

// ---------------------------------------------------------------- attention
// qkv_c: [B_CHUNK*12][224][192] bf16 (cols 0:32 q, 32:64 k, 64:192 v)
// ab: [12][196][224] f32, attn_c out: [B_CHUNK*196][1536] bf16
__global__ __launch_bounds__(512) void attn_kernel(
    const bf16* __restrict__ qkv_c, const float* __restrict__ ab,
    bf16* __restrict__ attn_c)
{
    __shared__ bf16 k_s[224 * 40];
    __shared__ bf16 vT_s[128 * 232];
    __shared__ bf16 p_s[8 * 16 * 232];
    int bh = blockIdx.x;
    int bl = bh / NH, h = bh - bl * NH;
    const bf16* base = qkv_c + (size_t)bh * NPAD * 192;
    int t = threadIdx.x;

    // stage K (rows >=196 zeroed)
    for (int c = t; c < 224 * 4; c += 512) {
        int r = c >> 2, g = c & 3;
        bf16x8 v;
        if (r < N_TOK) v = *(const bf16x8*)(base + (size_t)r * 192 + 32 + g * 8);
        else {
#pragma unroll
            for (int j = 0; j < 8; ++j) v[j] = (bf16)0.f;
        }
        *(bf16x8*)&k_s[r * 40 + g * 8] = v;
    }
    // stage V transposed (cols m>=196 zeroed); r fastest across lanes -> conflict-free writes
    for (int c = t; c < 224 * 16; c += 512) {
        int r = c % 224, g = c / 224;
        bf16x8 v;
        if (r < N_TOK) v = *(const bf16x8*)(base + (size_t)r * 192 + 64 + g * 8);
        else {
#pragma unroll
            for (int j = 0; j < 8; ++j) v[j] = (bf16)0.f;
        }
#pragma unroll
        for (int j = 0; j < 8; ++j) vT_s[(g * 8 + j) * 232 + r] = v[j];
    }
    __syncthreads();

    int lane = t & 63, wid = t >> 6;
    int lr = lane & 15, lg = lane >> 4, lk = lg * 8;
    const float SCL = 0.17677669529663687f;  // 32^-0.5
    const float L2E = 1.4426950408889634f;

    for (int tile = wid; tile < 13; tile += 8) {
        int n0 = tile * 16;
        bf16x8 aq = *(const bf16x8*)(base + (size_t)(n0 + lr) * 192 + lk);
        f32x4 S[14];
#pragma unroll
        for (int mt = 0; mt < 14; ++mt) {
            bf16x8 bk = *(const bf16x8*)&k_s[(mt * 16 + lr) * 40 + lk];
            f32x4 z = (f32x4){0.f, 0.f, 0.f, 0.f};
            S[mt] = __builtin_amdgcn_mfma_f32_16x16x32_bf16(aq, bk, z, 0, 0, 0);
        }
        const float* abr[4];
#pragma unroll
        for (int r = 0; r < 4; ++r) {
            int nr = n0 + lg * 4 + r;
            if (nr > N_TOK - 1) nr = N_TOK - 1;
            abr[r] = ab + ((size_t)h * N_TOK + nr) * NPAD + lr;
        }
        float mx[4] = {-1e30f, -1e30f, -1e30f, -1e30f};
#pragma unroll
        for (int mt = 0; mt < 14; ++mt)
#pragma unroll
            for (int r = 0; r < 4; ++r) {
                float sv = S[mt][r] * SCL + abr[r][mt * 16];
                S[mt][r] = sv;
                mx[r] = fmaxf(mx[r], sv);
            }
#pragma unroll
        for (int d = 1; d < 16; d <<= 1)
#pragma unroll
            for (int r = 0; r < 4; ++r)
                mx[r] = fmaxf(mx[r], __shfl_xor(mx[r], d, 64));
        float sum[4] = {0.f, 0.f, 0.f, 0.f};
#pragma unroll
        for (int mt = 0; mt < 14; ++mt)
#pragma unroll
            for (int r = 0; r < 4; ++r) {
                float p = exp2f((S[mt][r] - mx[r]) * L2E);
                sum[r] += p;
                p_s[((size_t)wid * 16 + lg * 4 + r) * 232 + mt * 16 + lr] = (bf16)p;
            }
#pragma unroll
        for (int d = 1; d < 16; d <<= 1)
#pragma unroll
            for (int r = 0; r < 4; ++r)
                sum[r] += __shfl_xor(sum[r], d, 64);
        float rs[4];
#pragma unroll
        for (int r = 0; r < 4; ++r) rs[r] = 1.f / sum[r];

        bf16x8 pa[7];
#pragma unroll
        for (int ks = 0; ks < 7; ++ks)
            pa[ks] = *(bf16x8*)&p_s[((size_t)wid * 16 + lr) * 232 + ks * 32 + lk];
        f32x4 acc[8];
#pragma unroll
        for (int dt = 0; dt < 8; ++dt) acc[dt] = (f32x4){0.f, 0.f, 0.f, 0.f};
#pragma unroll
        for (int ks = 0; ks < 7; ++ks)
#pragma unroll
            for (int dt = 0; dt < 8; ++dt) {
                bf16x8 bv = *(const bf16x8*)&vT_s[(dt * 16 + lr) * 232 + ks * 32 + lk];
                acc[dt] = __builtin_amdgcn_mfma_f32_16x16x32_bf16(pa[ks], bv, acc[dt], 0, 0, 0);
            }
#pragma unroll
        for (int dt = 0; dt < 8; ++dt)
#pragma unroll
            for (int r = 0; r < 4; ++r) {
                int n = n0 + lg * 4 + r;
                if (n < N_TOK) {
                    float v = acc[dt][r] * rs[r];
                    float hs = v * fminf(fmaxf(v + 3.f, 0.f), 6.f) * (1.f / 6.f);
                    attn_c[((size_t)bl * N_TOK + n) * 1536 + h * 128 + dt * 16 + lr] = (bf16)hs;
                }
            }
    }
}

// ---------------------------------------------------------------- proj GEMM
// aio: [MROWS][1536] bf16, w: [384][1536] f32, out: [MROWS][384] f32
__global__ __launch_bounds__(256) void proj_gemm(
    const bf16* __restrict__ aio, const float* __restrict__ w,
    const float* __restrict__ sp, const float* __restrict__ bp,
    float* __restrict__ out)
{
    __shared__ bf16 As[128 * 40];
    __shared__ bf16 Bs[128 * 40];
    int t = threadIdx.x;
    int m0 = blockIdx.x * 128;
    int n0 = blockIdx.y * 128;
    int lane = t & 63, wid = t >> 6;
    int qr = (wid >> 1) * 64, qc = (wid & 1) * 64;
    int lr = lane & 15, lg = lane >> 4, lk = lg * 8;

    f32x4 acc[4][4];
#pragma unroll
    for (int fi = 0; fi < 4; ++fi)
#pragma unroll
        for (int fj = 0; fj < 4; ++fj)
            acc[fi][fj] = (f32x4){0.f, 0.f, 0.f, 0.f};

    for (int kt = 0; kt < 1536 / 32; ++kt) {
        int k0 = kt * 32;
#pragma unroll
        for (int i = 0; i < 2; ++i) {
            int c = t + i * 256;
            int r = c >> 2, kk = (c & 3) * 8;
            *(bf16x8*)&As[r * 40 + kk] =
                *(const bf16x8*)(aio + (size_t)(m0 + r) * 1536 + k0 + kk);
            const float4* sb = (const float4*)(w + (size_t)(n0 + r) * 1536 + k0 + kk);
            float4 b0 = sb[0], b1 = sb[1];
            bf16x8 vb;
            vb[0] = (bf16)b0.x; vb[1] = (bf16)b0.y; vb[2] = (bf16)b0.z; vb[3] = (bf16)b0.w;
            vb[4] = (bf16)b1.x; vb[5] = (bf16)b1.y; vb[6] = (bf16)b1.z; vb[7] = (bf16)b1.w;
            *(bf16x8*)&Bs[r * 40 + kk] = vb;
        }
        __syncthreads();
        bf16x8 a[4], b[4];
#pragma unroll
        for (int f = 0; f < 4; ++f) {
            a[f] = *(bf16x8*)&As[(qr + f * 16 + lr) * 40 + lk];
            b[f] = *(bf16x8*)&Bs[(qc + f * 16 + lr) * 40 + lk];
        }
#pragma unroll
        for (int fi = 0; fi < 4; ++fi)
#pragma unroll
            for (int fj = 0; fj < 4; ++fj)
                acc[fi][fj] = __builtin_amdgcn_mfma_f32_16x16x32_bf16(a[fi], b[fj], acc[fi][fj], 0, 0, 0);
        __syncthreads();
    }

#pragma unroll
    for (int fj = 0; fj < 4; ++fj) {
        int col = n0 + qc + fj * 16 + lr;
        float s = sp[col], bb = bp[col];
#pragma unroll
        for (int fi = 0; fi < 4; ++fi) {
            int rb = m0 + qr + fi * 16 + lg * 4;
#pragma unroll
            for (int r = 0; r < 4; ++r) {
                int row = rb + r;
                out[(size_t)row * DIM_ + col] = acc[fi][fj][r] * s + bb;
            }
        }
    }
}

// ---------------------------------------------------------------- launch
extern "C" void kernel_launch(void* const* d_in, const int* in_sizes, int n_in,
                              void* d_out, int out_size, void* d_ws, size_t ws_size,
                              hipStream_t stream)
{
    const float* x          = (const float*)d_in[0];
    const float* qkv_w      = (const float*)d_in[1];
    const float* qkv_gamma  = (const float*)d_in[2];
    const float* qkv_beta   = (const float*)d_in[3];
    const float* qkv_mean   = (const float*)d_in[4];
    const float* qkv_var    = (const float*)d_in[5];
    const float* abias      = (const float*)d_in[6];
    const float* proj_w     = (const float*)d_in[7];
    const float* proj_gamma = (const float*)d_in[8];
    const float* proj_beta  = (const float*)d_in[9];
    const float* proj_mean  = (const float*)d_in[10];
    const float* proj_var   = (const float*)d_in[11];
    const int*   bias_idxs  = (const int*)d_in[12];
    float* out = (float*)d_out;

    char* wp = (char*)d_ws;
    auto alloc = [&](size_t bytes) {
        char* r = wp;
        wp += (bytes + 255) & ~(size_t)255;
        return r;
    };
    float* sqkv  = (float*)alloc((size_t)HQKV * 4);
    float* bqkv  = (float*)alloc((size_t)HQKV * 4);
    float* sproj = (float*)alloc((size_t)DIM_ * 4);
    float* bproj = (float*)alloc((size_t)DIM_ * 4);
    float* ab    = (float*)alloc((size_t)NH * N_TOK * NPAD * 4);
    bf16* qkv_c  = (bf16*)alloc((size_t)B_CHUNK * NH * NPAD * 192 * 2);
    bf16* attn_c = (bf16*)alloc((size_t)B_CHUNK * N_TOK * 1536 * 2);

    int prep_grid = (NH * N_TOK * NPAD + 255) / 256;  // 2058
    prep_kernel<<<prep_grid, 256, 0, stream>>>(
        qkv_gamma, qkv_beta, qkv_mean, qkv_var,
        proj_gamma, proj_beta, proj_mean, proj_var,
        abias, bias_idxs, sqkv, bqkv, sproj, bproj, ab);

    for (int c = 0; c < 256 / B_CHUNK; ++c) {
        const float* xc = x + (size_t)c * B_CHUNK * N_TOK * DIM_;
        float* oc = out + (size_t)c * B_CHUNK * N_TOK * DIM_;
        qkv_gemm<<<dim3(MROWS / 128, HQKV / 128), 256, 0, stream>>>(
            xc, qkv_w, sqkv, bqkv, qkv_c);
        attn_kernel<<<dim3(B_CHUNK * NH), 512, 0, stream>>>(qkv_c, ab, attn_c);
        proj_gemm<<<dim3(MROWS / 128, DIM_ / 128), 256, 0, stream>>>(
            attn_c, proj_w, sproj, bproj, oc);
    }
}

// Round 2
// 594.837 us; speedup vs baseline: 1.6720x; 1.6720x over previous
//
#include <hip/hip_runtime.h>
#include <hip/hip_bf16.h>
#include <cstdint>
#include <cstddef>

typedef __bf16 bf16;
typedef bf16 bf16x8 __attribute__((ext_vector_type(8)));
typedef float f32x4 __attribute__((ext_vector_type(4)));

#define N_TOK 196
#define DIM_ 384
#define HQKV 2304
#define NH 12
#define NPAD 224          // padded token count (m dim), 7*32
#define B_TOT 256

// ---------------------------------------------------------------- prep
__global__ __launch_bounds__(256) void prep_kernel(
    const float* __restrict__ qg, const float* __restrict__ qb,
    const float* __restrict__ qm, const float* __restrict__ qv,
    const float* __restrict__ pg, const float* __restrict__ pb,
    const float* __restrict__ pm, const float* __restrict__ pv,
    const float* __restrict__ abias, const int* __restrict__ idxs,
    float* __restrict__ sqkv, float* __restrict__ bqkv,
    float* __restrict__ sproj, float* __restrict__ bproj,
    float* __restrict__ ab)
{
    int i = blockIdx.x * 256 + threadIdx.x;
    if (i < HQKV) {
        float s = qg[i] * rsqrtf(qv[i] + 1e-5f);
        sqkv[i] = s;
        bqkv[i] = qb[i] - qm[i] * s;
    }
    if (i < DIM_) {
        float s = pg[i] * rsqrtf(pv[i] + 1e-5f);
        sproj[i] = s;
        bproj[i] = pb[i] - pm[i] * s;
    }
    if (i < NH * N_TOK * NPAD) {
        int h = i / (N_TOK * NPAD);
        int rem = i - h * (N_TOK * NPAD);
        int n = rem / NPAD;
        int m = rem - n * NPAD;
        ab[i] = (m < N_TOK) ? abias[h * N_TOK + idxs[n * N_TOK + m]] : -1e30f;
    }
}

// ---------------------------------------------------------------- f32 -> bf16 convert
__global__ __launch_bounds__(256) void convert_kernel(
    const float* __restrict__ src, bf16* __restrict__ dst, int n4)
{
    int stride = gridDim.x * 256;
    for (int i = blockIdx.x * 256 + threadIdx.x; i < n4; i += stride) {
        float4 v = ((const float4*)src)[i];
        bf16 o[4] = {(bf16)v.x, (bf16)v.y, (bf16)v.z, (bf16)v.w};
        *(uint2*)&dst[(size_t)i * 4] = *(uint2*)o;
    }
}

// ---------------------------------------------------------------- QKV GEMM (bf16 x bf16)
// x: [M][384] bf16, w: [2304][384] bf16
// out: qkv_c [B_CHUNK*12][224][192] bf16 (rows >=196 untouched)
__global__ __launch_bounds__(256) void qkv_gemm(
    const bf16* __restrict__ x, const bf16* __restrict__ w,
    const float* __restrict__ sq, const float* __restrict__ bq,
    bf16* __restrict__ qkv_c)
{
    __shared__ bf16 As[128 * 40];
    __shared__ bf16 Bs[128 * 40];
    int t = threadIdx.x;
    int m0 = blockIdx.x * 128;
    int n0 = blockIdx.y * 128;
    int lane = t & 63, wid = t >> 6;
    int qr = (wid >> 1) * 64, qc = (wid & 1) * 64;
    int lr = lane & 15, lg = lane >> 4, lk = lg * 8;

    f32x4 acc[4][4];
#pragma unroll
    for (int fi = 0; fi < 4; ++fi)
#pragma unroll
        for (int fj = 0; fj < 4; ++fj)
            acc[fi][fj] = (f32x4){0.f, 0.f, 0.f, 0.f};

    int r = t >> 2, kk = (t & 3) * 8;
    for (int kt = 0; kt < DIM_ / 32; ++kt) {
        int k0 = kt * 32;
        {
            *(bf16x8*)&As[r * 40 + kk] =
                *(const bf16x8*)(x + (size_t)(m0 + r) * DIM_ + k0 + kk);
            *(bf16x8*)&As[(r + 64) * 40 + kk] =
                *(const bf16x8*)(x + (size_t)(m0 + r + 64) * DIM_ + k0 + kk);
            *(bf16x8*)&Bs[r * 40 + kk] =
                *(const bf16x8*)(w + (size_t)(n0 + r) * DIM_ + k0 + kk);
            *(bf16x8*)&Bs[(r + 64) * 40 + kk] =
                *(const bf16x8*)(w + (size_t)(n0 + r + 64) * DIM_ + k0 + kk);
        }
        __syncthreads();
        bf16x8 a[4], b[4];
#pragma unroll
        for (int f = 0; f < 4; ++f) {
            a[f] = *(bf16x8*)&As[(qr + f * 16 + lr) * 40 + lk];
            b[f] = *(bf16x8*)&Bs[(qc + f * 16 + lr) * 40 + lk];
        }
#pragma unroll
        for (int fi = 0; fi < 4; ++fi)
#pragma unroll
            for (int fj = 0; fj < 4; ++fj)
                acc[fi][fj] = __builtin_amdgcn_mfma_f32_16x16x32_bf16(a[fi], b[fj], acc[fi][fj], 0, 0, 0);
        __syncthreads();
    }

#pragma unroll
    for (int fj = 0; fj < 4; ++fj) {
        int col = n0 + qc + fj * 16 + lr;
        float s = sq[col], bb = bq[col];
        int h = col / 192, cc = col - h * 192;
#pragma unroll
        for (int fi = 0; fi < 4; ++fi) {
            int rb = m0 + qr + fi * 16 + lg * 4;
#pragma unroll
            for (int rr = 0; rr < 4; ++rr) {
                int row = rb + rr;
                int bl = row / N_TOK, n = row - bl * N_TOK;
                float v = acc[fi][fj][rr] * s + bb;
                qkv_c[((size_t)(bl * NH + h) * NPAD + n) * 192 + cc] = (bf16)v;
            }
        }
    }
}

// ---------------------------------------------------------------- attention
// qkv_c: [B_CHUNK*12][224][192] bf16 (cols 0:32 q, 32:64 k, 64:192 v)
// ab: [12][196][224] f32, attn_c out: [B_CHUNK*196][1536] bf16
__global__ __launch_bounds__(512) void attn_kernel(
    const bf16* __restrict__ qkv_c, const float* __restrict__ ab,
    bf16* __restrict__ attn_c)
{
    __shared__ bf16 k_s[224 * 40];
    __shared__ bf16 vT_s[128 * 232];
    __shared__ bf16 p_s[8 * 16 * 232];
    int bh = blockIdx.x;
    int bl = bh / NH, h = bh - bl * NH;
    const bf16* base = qkv_c + (size_t)bh * NPAD * 192;
    int t = threadIdx.x;

    // stage K (rows >=196 zeroed)
    for (int c = t; c < 224 * 4; c += 512) {
        int r = c >> 2, g = c & 3;
        bf16x8 v;
        if (r < N_TOK) v = *(const bf16x8*)(base + (size_t)r * 192 + 32 + g * 8);
        else {
#pragma unroll
            for (int j = 0; j < 8; ++j) v[j] = (bf16)0.f;
        }
        *(bf16x8*)&k_s[r * 40 + g * 8] = v;
    }
    // stage V transposed (cols m>=196 zeroed)
    for (int c = t; c < 224 * 16; c += 512) {
        int r = c % 224, g = c / 224;
        bf16x8 v;
        if (r < N_TOK) v = *(const bf16x8*)(base + (size_t)r * 192 + 64 + g * 8);
        else {
#pragma unroll
            for (int j = 0; j < 8; ++j) v[j] = (bf16)0.f;
        }
#pragma unroll
        for (int j = 0; j < 8; ++j) vT_s[(g * 8 + j) * 232 + r] = v[j];
    }
    __syncthreads();

    int lane = t & 63, wid = t >> 6;
    int lr = lane & 15, lg = lane >> 4, lk = lg * 8;
    const float SCL = 0.17677669529663687f;  // 32^-0.5
    const float L2E = 1.4426950408889634f;

    for (int tile = wid; tile < 13; tile += 8) {
        int n0 = tile * 16;
        bf16x8 aq = *(const bf16x8*)(base + (size_t)(n0 + lr) * 192 + lk);
        f32x4 S[14];
#pragma unroll
        for (int mt = 0; mt < 14; ++mt) {
            bf16x8 bk = *(const bf16x8*)&k_s[(mt * 16 + lr) * 40 + lk];
            f32x4 z = (f32x4){0.f, 0.f, 0.f, 0.f};
            S[mt] = __builtin_amdgcn_mfma_f32_16x16x32_bf16(aq, bk, z, 0, 0, 0);
        }
        const float* abr[4];
#pragma unroll
        for (int rr = 0; rr < 4; ++rr) {
            int nr = n0 + lg * 4 + rr;
            if (nr > N_TOK - 1) nr = N_TOK - 1;
            abr[rr] = ab + ((size_t)h * N_TOK + nr) * NPAD + lr;
        }
        float mx[4] = {-1e30f, -1e30f, -1e30f, -1e30f};
#pragma unroll
        for (int mt = 0; mt < 14; ++mt)
#pragma unroll
            for (int rr = 0; rr < 4; ++rr) {
                float sv = S[mt][rr] * SCL + abr[rr][mt * 16];
                S[mt][rr] = sv;
                mx[rr] = fmaxf(mx[rr], sv);
            }
#pragma unroll
        for (int d = 1; d < 16; d <<= 1)
#pragma unroll
            for (int rr = 0; rr < 4; ++rr)
                mx[rr] = fmaxf(mx[rr], __shfl_xor(mx[rr], d, 64));
        float sum[4] = {0.f, 0.f, 0.f, 0.f};
#pragma unroll
        for (int mt = 0; mt < 14; ++mt)
#pragma unroll
            for (int rr = 0; rr < 4; ++rr) {
                float p = exp2f((S[mt][rr] - mx[rr]) * L2E);
                sum[rr] += p;
                p_s[((size_t)wid * 16 + lg * 4 + rr) * 232 + mt * 16 + lr] = (bf16)p;
            }
#pragma unroll
        for (int d = 1; d < 16; d <<= 1)
#pragma unroll
            for (int rr = 0; rr < 4; ++rr)
                sum[rr] += __shfl_xor(sum[rr], d, 64);
        float rs[4];
#pragma unroll
        for (int rr = 0; rr < 4; ++rr) rs[rr] = 1.f / sum[rr];

        bf16x8 pa[7];
#pragma unroll
        for (int ks = 0; ks < 7; ++ks)
            pa[ks] = *(bf16x8*)&p_s[((size_t)wid * 16 + lr) * 232 + ks * 32 + lk];
        f32x4 acc[8];
#pragma unroll
        for (int dt = 0; dt < 8; ++dt) acc[dt] = (f32x4){0.f, 0.f, 0.f, 0.f};
#pragma unroll
        for (int ks = 0; ks < 7; ++ks)
#pragma unroll
            for (int dt = 0; dt < 8; ++dt) {
                bf16x8 bv = *(const bf16x8*)&vT_s[(dt * 16 + lr) * 232 + ks * 32 + lk];
                acc[dt] = __builtin_amdgcn_mfma_f32_16x16x32_bf16(pa[ks], bv, acc[dt], 0, 0, 0);
            }
#pragma unroll
        for (int dt = 0; dt < 8; ++dt)
#pragma unroll
            for (int rr = 0; rr < 4; ++rr) {
                int n = n0 + lg * 4 + rr;
                if (n < N_TOK) {
                    float v = acc[dt][rr] * rs[rr];
                    float hs = v * fminf(fmaxf(v + 3.f, 0.f), 6.f) * (1.f / 6.f);
                    attn_c[((size_t)bl * N_TOK + n) * 1536 + h * 128 + dt * 16 + lr] = (bf16)hs;
                }
            }
    }
}

// ---------------------------------------------------------------- proj GEMM
// aio: [M][1536] bf16, w: [384][1536] bf16, out: [M][384] f32
__global__ __launch_bounds__(256) void proj_gemm(
    const bf16* __restrict__ aio, const bf16* __restrict__ w,
    const float* __restrict__ sp, const float* __restrict__ bp,
    float* __restrict__ out)
{
    __shared__ bf16 As[128 * 40];
    __shared__ bf16 Bs[128 * 40];
    int t = threadIdx.x;
    int m0 = blockIdx.x * 128;
    int n0 = blockIdx.y * 128;
    int lane = t & 63, wid = t >> 6;
    int qr = (wid >> 1) * 64, qc = (wid & 1) * 64;
    int lr = lane & 15, lg = lane >> 4, lk = lg * 8;

    f32x4 acc[4][4];
#pragma unroll
    for (int fi = 0; fi < 4; ++fi)
#pragma unroll
        for (int fj = 0; fj < 4; ++fj)
            acc[fi][fj] = (f32x4){0.f, 0.f, 0.f, 0.f};

    int r = t >> 2, kk = (t & 3) * 8;
    for (int kt = 0; kt < 1536 / 32; ++kt) {
        int k0 = kt * 32;
        {
            *(bf16x8*)&As[r * 40 + kk] =
                *(const bf16x8*)(aio + (size_t)(m0 + r) * 1536 + k0 + kk);
            *(bf16x8*)&As[(r + 64) * 40 + kk] =
                *(const bf16x8*)(aio + (size_t)(m0 + r + 64) * 1536 + k0 + kk);
            *(bf16x8*)&Bs[r * 40 + kk] =
                *(const bf16x8*)(w + (size_t)(n0 + r) * 1536 + k0 + kk);
            *(bf16x8*)&Bs[(r + 64) * 40 + kk] =
                *(const bf16x8*)(w + (size_t)(n0 + r + 64) * 1536 + k0 + kk);
        }
        __syncthreads();
        bf16x8 a[4], b[4];
#pragma unroll
        for (int f = 0; f < 4; ++f) {
            a[f] = *(bf16x8*)&As[(qr + f * 16 + lr) * 40 + lk];
            b[f] = *(bf16x8*)&Bs[(qc + f * 16 + lr) * 40 + lk];
        }
#pragma unroll
        for (int fi = 0; fi < 4; ++fi)
#pragma unroll
            for (int fj = 0; fj < 4; ++fj)
                acc[fi][fj] = __builtin_amdgcn_mfma_f32_16x16x32_bf16(a[fi], b[fj], acc[fi][fj], 0, 0, 0);
        __syncthreads();
    }

#pragma unroll
    for (int fj = 0; fj < 4; ++fj) {
        int col = n0 + qc + fj * 16 + lr;
        float s = sp[col], bb = bp[col];
#pragma unroll
        for (int fi = 0; fi < 4; ++fi) {
            int rb = m0 + qr + fi * 16 + lg * 4;
#pragma unroll
            for (int rr = 0; rr < 4; ++rr) {
                int row = rb + rr;
                out[(size_t)row * DIM_ + col] = acc[fi][fj][rr] * s + bb;
            }
        }
    }
}

// ---------------------------------------------------------------- launch
extern "C" void kernel_launch(void* const* d_in, const int* in_sizes, int n_in,
                              void* d_out, int out_size, void* d_ws, size_t ws_size,
                              hipStream_t stream)
{
    const float* x          = (const float*)d_in[0];
    const float* qkv_w      = (const float*)d_in[1];
    const float* qkv_gamma  = (const float*)d_in[2];
    const float* qkv_beta   = (const float*)d_in[3];
    const float* qkv_mean   = (const float*)d_in[4];
    const float* qkv_var    = (const float*)d_in[5];
    const float* abias      = (const float*)d_in[6];
    const float* proj_w     = (const float*)d_in[7];
    const float* proj_gamma = (const float*)d_in[8];
    const float* proj_beta  = (const float*)d_in[9];
    const float* proj_mean  = (const float*)d_in[10];
    const float* proj_var   = (const float*)d_in[11];
    const int*   bias_idxs  = (const int*)d_in[12];
    float* out = (float*)d_out;

    char* wp = (char*)d_ws;
    auto alloc = [&](size_t bytes) {
        char* r = wp;
        wp += (bytes + 255) & ~(size_t)255;
        return r;
    };
    float* sqkv  = (float*)alloc((size_t)HQKV * 4);
    float* bqkv  = (float*)alloc((size_t)HQKV * 4);
    float* sproj = (float*)alloc((size_t)DIM_ * 4);
    float* bproj = (float*)alloc((size_t)DIM_ * 4);
    float* ab    = (float*)alloc((size_t)NH * N_TOK * NPAD * 4);
    bf16* xb     = (bf16*)alloc((size_t)B_TOT * N_TOK * DIM_ * 2);
    bf16* wb     = (bf16*)alloc((size_t)HQKV * DIM_ * 2);
    bf16* pwb    = (bf16*)alloc((size_t)DIM_ * 1536 * 2);

    // pick largest batch-chunk that fits in workspace (ws_size is constant
    // across calls -> deterministic)
    size_t fixed_used = (size_t)(wp - (char*)d_ws);
    auto per_chunk = [](int bc) {
        size_t q = ((size_t)bc * NH * NPAD * 192 * 2 + 255) & ~(size_t)255;
        size_t a = ((size_t)bc * N_TOK * 1536 * 2 + 255) & ~(size_t)255;
        return q + a;
    };
    int bchunk = 32;
    const int cands[4] = {256, 128, 64, 32};
    for (int ci = 0; ci < 4; ++ci) {
        if (fixed_used + per_chunk(cands[ci]) <= ws_size) { bchunk = cands[ci]; break; }
    }
    bf16* qkv_c  = (bf16*)alloc((size_t)bchunk * NH * NPAD * 192 * 2);
    bf16* attn_c = (bf16*)alloc((size_t)bchunk * N_TOK * 1536 * 2);

    int prep_grid = (NH * N_TOK * NPAD + 255) / 256;  // 2058
    prep_kernel<<<prep_grid, 256, 0, stream>>>(
        qkv_gamma, qkv_beta, qkv_mean, qkv_var,
        proj_gamma, proj_beta, proj_mean, proj_var,
        abias, bias_idxs, sqkv, bqkv, sproj, bproj, ab);

    convert_kernel<<<2048, 256, 0, stream>>>(x, xb, B_TOT * N_TOK * DIM_ / 4);
    convert_kernel<<<512, 256, 0, stream>>>(qkv_w, wb, HQKV * DIM_ / 4);
    convert_kernel<<<512, 256, 0, stream>>>(proj_w, pwb, DIM_ * 1536 / 4);

    int mrows = bchunk * N_TOK;
    for (int c = 0; c < B_TOT / bchunk; ++c) {
        const bf16* xc = xb + (size_t)c * bchunk * N_TOK * DIM_;
        float* oc = out + (size_t)c * bchunk * N_TOK * DIM_;
        qkv_gemm<<<dim3(mrows / 128, HQKV / 128), 256, 0, stream>>>(
            xc, wb, sqkv, bqkv, qkv_c);
        attn_kernel<<<dim3(bchunk * NH), 512, 0, stream>>>(qkv_c, ab, attn_c);
        proj_gemm<<<dim3(mrows / 128, DIM_ / 128), 256, 0, stream>>>(
            attn_c, pwb, sproj, bproj, oc);
    }
}